// Round 1
// baseline (417.645 us; speedup 1.0000x reference)
//
#include <hip/hip_runtime.h>

// Problem: B=4096 rows, N=16384 cols, fp32.
// out = where(outlier(x - roll(x,1,axis=1)), 0, nan_to_zero(x))
// lower/upper = mean_grad -/+ 4*sqrt(var_grad), per column.

#define N_COLS 16384
#define COLS4  (N_COLS / 4)          // 4096 float4 per row
#define COLS4_SHIFT 12               // log2(COLS4)
#define COLS4_MASK  (COLS4 - 1)

__device__ __forceinline__ float nan_clean(float v) {
    unsigned u = __float_as_uint(v);
    // exponent all-ones => NaN or Inf => 0
    return ((u & 0x7f800000u) == 0x7f800000u) ? 0.0f : v;
}

__global__ __launch_bounds__(256) void correction_kernel(
    const float* __restrict__ x,
    const float* __restrict__ mean_grad,
    const float* __restrict__ var_grad,
    float* __restrict__ out)
{
    int t = blockIdx.x * blockDim.x + threadIdx.x;
    int row  = t >> COLS4_SHIFT;
    int col4 = t & COLS4_MASK;
    int j    = col4 << 2;                      // starting column of this float4
    long base = (long)row * N_COLS + j;

    float4 x4 = *(const float4*)(x + base);
    int jprev = (j + N_COLS - 1) & (N_COLS - 1);   // circular previous column
    float prev = x[(long)row * N_COLS + jprev];

    float c0 = nan_clean(x4.x);
    float c1 = nan_clean(x4.y);
    float c2 = nan_clean(x4.z);
    float c3 = nan_clean(x4.w);
    float cp = nan_clean(prev);

    // per-column bounds (cached: 64 KiB arrays, reused by all 4096 rows)
    float4 m4 = *(const float4*)(mean_grad + j);
    float4 v4 = *(const float4*)(var_grad + j);

    float s0 = 4.0f * sqrtf(v4.x);
    float s1 = 4.0f * sqrtf(v4.y);
    float s2 = 4.0f * sqrtf(v4.z);
    float s3 = 4.0f * sqrtf(v4.w);

    float d0 = c0 - cp;
    float d1 = c1 - c0;
    float d2 = c2 - c1;
    float d3 = c3 - c2;

    float4 o;
    o.x = (d0 < m4.x - s0 || d0 > m4.x + s0) ? 0.0f : c0;
    o.y = (d1 < m4.y - s1 || d1 > m4.y + s1) ? 0.0f : c1;
    o.z = (d2 < m4.z - s2 || d2 > m4.z + s2) ? 0.0f : c2;
    o.w = (d3 < m4.w - s3 || d3 > m4.w + s3) ? 0.0f : c3;

    *(float4*)(out + base) = o;
}

extern "C" void kernel_launch(void* const* d_in, const int* in_sizes, int n_in,
                              void* d_out, int out_size, void* d_ws, size_t ws_size,
                              hipStream_t stream) {
    const float* x  = (const float*)d_in[0];   // output  [B, N]
    const float* mg = (const float*)d_in[1];   // mean_grad [N]
    const float* vg = (const float*)d_in[2];   // var_grad  [N]
    float* out = (float*)d_out;

    int B = in_sizes[0] / N_COLS;              // 4096
    long total_threads = (long)B * COLS4;      // one thread per float4
    int block = 256;
    int grid = (int)((total_threads + block - 1) / block);

    correction_kernel<<<grid, block, 0, stream>>>(x, mg, vg, out);
}